// Round 6
// baseline (254.209 us; speedup 1.0000x reference)
//
#include <hip/hip_runtime.h>

// Blockwise 16x16 2D DCT (out = K @ T @ K^T), fp32, memory-bound.
// Block-level 16x256 strips (1KB-row loads AND stores), double-buffered
// global_load_lds, counted vmcnt with stores-last issue order (3-iter store
// retirement slack), 2 barriers/iter (U transpose is wave-local).
// 512 persistent blocks x 256 thr, exactly 2 blocks/CU, 48 strips each.

#define IMG_W   1024
#define SCOLS   256
#define INBUF   4096        // 16 rows x 256 floats, no pad (row reads are lane-consecutive)
#define UOFF    8192        // after 2 in-buffers
#define USTRIDE 20          // 80B rows: 16B-aligned, bank-balanced b128 reads
#define UTILE   336         // 16*20 + 16: per-tile region
#define STAGEOFF 13568      // 8192 + 16*336
#define SSTRIDE 260         // stage row stride (bank-balanced b128 r/w)
#define LDS_FLOATS 17728    // 13568 + 16*260 = 70912 B -> exactly 2 blocks/CU

typedef float floatx4 __attribute__((ext_vector_type(4)));

__device__ __forceinline__ void gload_lds16(const float* gp, float* lp) {
    // async 16B/lane global->LDS; LDS dest = wave-uniform base + lane*16
    __builtin_amdgcn_global_load_lds(
        (const __attribute__((address_space(1))) void*)gp,
        (__attribute__((address_space(3))) void*)lp,
        16, 0, 0);
}

__global__ __launch_bounds__(256, 2) void dct16_kernel(
    const float* __restrict__ x,
    const float* __restrict__ kern,      // 16x16 DCT matrix, row-major
    float* __restrict__ out,
    int strips_per_block)
{
    __shared__ float lds[LDS_FLOATS];

    const int tid  = threadIdx.x;
    const int lane = tid & 63;
    const int wid  = tid >> 6;

    const int s0 = blockIdx.x * strips_per_block;
    const int ns = strips_per_block;     // uniform (24576 = 512*48), ns >= 3

    // strip s: 16 rows x 256 cols. band = s>>2, quarter = s&3.
    auto sbase = [](int s) -> size_t {
        return (size_t)(s >> 2) * (16 * IMG_W) + (size_t)(s & 3) * SCOLS;
    };

    // 4 DMA instrs/wave, each one full 1KB row (row = 4*it + wid)
    auto dma = [&](int s, int b) {
        const float* g = x + sbase(s) + (size_t)wid * IMG_W + lane * 4;
        float* l = &lds[b * INBUF + wid * SCOLS];
        #pragma unroll
        for (int it = 0; it < 4; ++it)
            gload_lds16(g + (size_t)(4 * it) * IMG_W, l + it * 4 * SCOLS);
    };

    dma(s0 + 0, 0);
    dma(s0 + 1, 1);

    for (int k = 0; k < ns; ++k) {
        const int cur = k & 1;

        // Wait for strip k's DMA only. Per-wave queue (issue order, 4 ops each):
        //   ..., D_k, S_{k-2}, D_{k+1}, S_{k-1}  -> after D_k retires: 12 left.
        // In-order retirement => stores are only force-waited 3 iters after issue.
        if (k == 0)            { asm volatile("s_waitcnt vmcnt(4)"  ::: "memory"); }
        else if (k == 1)       { asm volatile("s_waitcnt vmcnt(8)"  ::: "memory"); }
        else if (k == ns - 1)  { asm volatile("s_waitcnt vmcnt(8)"  ::: "memory"); }
        else                   { asm volatile("s_waitcnt vmcnt(12)" ::: "memory"); }
        __builtin_amdgcn_s_barrier();        // B1: all waves' strip-k data visible
        asm volatile("" ::: "memory");

        const float* ibuf = &lds[cur * INBUF];

        // ---- Pass 1: U = K @ T. Thread = one column (c=tid). ----
        // Wave w owns cols [64w,64w+64) == tiles [4w,4w+4) -> U is WAVE-LOCAL,
        // no barrier needed between pass 1 and pass 2.
        {
            const int c  = tid;
            const int t  = c >> 4;
            const int cl = c & 15;
            float tv[16];
            #pragma unroll
            for (int j = 0; j < 16; ++j) tv[j] = ibuf[j * SCOLS + c];

            float u[16];
            #pragma unroll
            for (int i = 0; i < 16; ++i) u[i] = 0.0f;
            #pragma unroll
            for (int j = 0; j < 16; ++j) {
                float tj = tv[j];
                #pragma unroll
                for (int i = 0; i < 16; ++i)
                    u[i] = fmaf(kern[i * 16 + j], tj, u[i]);   // uniform -> s_load
            }

            float* U = &lds[UOFF + t * UTILE];
            #pragma unroll
            for (int i = 0; i < 16; ++i)
                U[i * USTRIDE + cl] = u[i];
        }

        // ---- Pass 2: out = U @ K^T. Thread = (tile, row). ----
        {
            const int t = tid >> 4;
            const int r = tid & 15;
            const float* Ur = &lds[UOFF + t * UTILE + r * USTRIDE];

            float ur[16];
            #pragma unroll
            for (int p = 0; p < 4; ++p) {
                floatx4 v = *reinterpret_cast<const floatx4*>(Ur + p * 4);
                ur[p*4+0] = v.x; ur[p*4+1] = v.y; ur[p*4+2] = v.z; ur[p*4+3] = v.w;
            }

            float o[16];
            #pragma unroll
            for (int m = 0; m < 16; ++m) {
                float a = 0.0f;
                #pragma unroll
                for (int l = 0; l < 16; ++l)
                    a = fmaf(ur[l], kern[m * 16 + l], a);
                o[m] = a;
            }

            // stage row r of tile t into the cross-wave stage buffer
            float* st = &lds[STAGEOFF + r * SSTRIDE + t * 16];
            #pragma unroll
            for (int f = 0; f < 4; ++f) {
                floatx4 v = { o[f*4+0], o[f*4+1], o[f*4+2], o[f*4+3] };
                *reinterpret_cast<floatx4*>(st + f * 4) = v;
            }
        }
        asm volatile("s_waitcnt lgkmcnt(0)" ::: "memory");
        __builtin_amdgcn_s_barrier();        // B3: stage complete
        asm volatile("" ::: "memory");
        // (stage is protected from next-iter overwrite by next iter's B1.)

        // ---- Store phase: read stage (1KB rows), prefetch k+2, store k ----
        {
            floatx4 sv[4];
            const float* stg = &lds[STAGEOFF];
            #pragma unroll
            for (int it = 0; it < 4; ++it) {
                int row = it * 4 + wid;
                sv[it] = *reinterpret_cast<const floatx4*>(stg + row * SSTRIDE + lane * 4);
            }

            // D_{k+2} into buf cur: safe, all waves' pass-1 reads done (B3)
            if (k + 2 < ns) dma(s0 + k + 2, cur);

            float* g = out + sbase(s0 + k) + (size_t)wid * IMG_W + lane * 4;
            #pragma unroll
            for (int it = 0; it < 4; ++it)
                __builtin_nontemporal_store(sv[it],
                    reinterpret_cast<floatx4*>(g + (size_t)(4 * it) * IMG_W));
        }
    }
}

extern "C" void kernel_launch(void* const* d_in, const int* in_sizes, int n_in,
                              void* d_out, int out_size, void* d_ws, size_t ws_size,
                              hipStream_t stream) {
    const float* x    = (const float*)d_in[0];
    const float* kern = (const float*)d_in[1];
    float* out        = (float*)d_out;

    const int n_img        = in_sizes[0] / (IMG_W * IMG_W);   // 96
    const int total_strips = n_img * 256;                     // 24576 strips of 16x256
    const int blocks       = 512;                             // exactly 2 per CU
    const int per_block    = total_strips / blocks;           // 48, exact

    dct16_kernel<<<blocks, 256, 0, stream>>>(x, kern, out, per_block);
}

// Round 7
// 168.056 us; speedup vs baseline: 1.5126x; 1.5126x over previous
//
#include <hip/hip_runtime.h>

// Blockwise 16x16 2D DCT (out = K @ T @ K^T), fp32, memory-bound.
// R7: 16 waves/CU (4 blocks x 4 waves), single LDS input buffer + REGISTER
// prefetch (global->VGPR early, ds_write late), U buffer doubles as store
// stage (wave-local in-order LDS), 2 barriers/iter, fast symmetric DCT
// (96 FMA + 24 add per 16-pt transform, contiguous kern s_loads).
// 1024 persistent blocks x 256 thr, 24 strips of 16x256 each.

#define IMG_W  1024
#define SCOLS  256
#define U0     4096         // U/stage region starts after ibuf
#define UTILE  336          // per-tile: 16 rows * 20 + 16 slack
#define USTR   20           // U row stride (80B, 16B-aligned, bank-rotating)
#define LDS_FLOATS 9472     // 4096 + 16*336 = 37888 B -> 4 blocks/CU

typedef float floatx4 __attribute__((ext_vector_type(4)));

// u[i] = sum_j K[i][j] * t[j], exploiting K[i][j] = +/- K[i][15-j] and the
// same symmetry one level down on the even rows. Exact for the DCT-II matrix.
__device__ __forceinline__ void dct16_fast(const float t[16],
                                           const float* __restrict__ kern,
                                           float u[16]) {
    float s[8], d[8];
    #pragma unroll
    for (int n = 0; n < 8; ++n) { s[n] = t[n] + t[15 - n]; d[n] = t[n] - t[15 - n]; }
    float ss[4], sd[4];
    #pragma unroll
    for (int n = 0; n < 4; ++n) { ss[n] = s[n] + s[7 - n]; sd[n] = s[n] - s[7 - n]; }
    #pragma unroll
    for (int k = 0; k < 4; ++k) {
        float a = 0.0f, b = 0.0f;
        #pragma unroll
        for (int n = 0; n < 4; ++n) {
            a = fmaf(kern[(4 * k) * 16 + n],     ss[n], a);   // contiguous row prefix
            b = fmaf(kern[(4 * k + 2) * 16 + n], sd[n], b);
        }
        u[4 * k] = a; u[4 * k + 2] = b;
    }
    #pragma unroll
    for (int k = 0; k < 8; ++k) {
        float a = 0.0f;
        #pragma unroll
        for (int n = 0; n < 8; ++n)
            a = fmaf(kern[(2 * k + 1) * 16 + n], d[n], a);
        u[2 * k + 1] = a;
    }
}

__global__ __launch_bounds__(256, 4) void dct16_kernel(
    const float* __restrict__ x,
    const float* __restrict__ kern,      // 16x16 DCT matrix, row-major
    float* __restrict__ out,
    int strips_per_block, int total_strips)
{
    __shared__ float lds[LDS_FLOATS];

    const int tid  = threadIdx.x;
    const int lane = tid & 63;
    const int wid  = tid >> 6;

    int s0 = blockIdx.x * strips_per_block;
    if (s0 >= total_strips) return;                 // uniform per block
    int ns = strips_per_block;
    if (s0 + ns > total_strips) ns = total_strips - s0;

    // strip s: 16 rows x 256 cols. band = s>>2, quarter = s&3.
    auto sbase = [](int s) -> size_t {
        return (size_t)(s >> 2) * (16 * IMG_W) + (size_t)(s & 3) * SCOLS;
    };

    floatx4 pre[4];                                 // prefetch regs (one strip/block)

    // load strip s into regs: instr f = row 4*wid+f, 1KB contiguous per instr
    auto load_strip = [&](int s) {
        const float* g = x + sbase(s) + (size_t)(4 * wid) * IMG_W + lane * 4;
        #pragma unroll
        for (int f = 0; f < 4; ++f)
            pre[f] = *reinterpret_cast<const floatx4*>(g + (size_t)f * IMG_W);
    };
    // regs -> ibuf (compiler inserts the counted vmcnt before first use of pre)
    auto write_strip = [&]() {
        #pragma unroll
        for (int f = 0; f < 4; ++f)
            *reinterpret_cast<floatx4*>(&lds[(4 * wid + f) * SCOLS + lane * 4]) = pre[f];
    };

    // prologue: strip s0 regs -> ibuf; prefetch s0+1
    load_strip(s0);
    write_strip();
    if (ns > 1) load_strip(s0 + 1);

    for (int k = 0; k < ns; ++k) {
        asm volatile("s_waitcnt lgkmcnt(0)" ::: "memory");
        __builtin_amdgcn_s_barrier();               // B_top: ibuf = strip k
        asm volatile("" ::: "memory");

        // ---- Pass 1: U = K @ T. Thread = column c = tid. ----
        {
            const int c  = tid;
            const int t  = c >> 4;
            const int cl = c & 15;
            float tv[16];
            #pragma unroll
            for (int j = 0; j < 16; ++j) tv[j] = lds[j * SCOLS + c];

            float u[16];
            dct16_fast(tv, kern, u);

            float* U = &lds[U0 + t * UTILE];
            #pragma unroll
            for (int i = 0; i < 16; ++i)
                U[i * USTR + cl] = u[i];
        }

        // ---- Pass 2: O = U @ K^T. Thread = (tile t, row r). Wave-local. ----
        {
            const int t = tid >> 4;
            const int r = tid & 15;
            float* Ur = &lds[U0 + t * UTILE + r * USTR];

            float ur[16];
            #pragma unroll
            for (int p = 0; p < 4; ++p) {
                floatx4 v = *reinterpret_cast<const floatx4*>(Ur + p * 4);
                ur[p*4+0] = v.x; ur[p*4+1] = v.y; ur[p*4+2] = v.z; ur[p*4+3] = v.w;
            }

            float o[16];
            dct16_fast(ur, kern, o);

            // overwrite own slots (same-wave in-order LDS: reads retire first)
            #pragma unroll
            for (int f = 0; f < 4; ++f) {
                floatx4 v = { o[f*4+0], o[f*4+1], o[f*4+2], o[f*4+3] };
                *reinterpret_cast<floatx4*>(Ur + f * 4) = v;
            }
        }
        asm volatile("s_waitcnt lgkmcnt(0)" ::: "memory");
        __builtin_amdgcn_s_barrier();               // B_mid: stage done, ibuf reads done
        asm volatile("" ::: "memory");

        // ---- Tail: stage-read, ds_write k+1, prefetch k+2, store k ----
        {
            // row = 4*wid+it; element col = lane*4+q -> tile lane>>2, col (lane&3)*4
            floatx4 sv[4];
            #pragma unroll
            for (int it = 0; it < 4; ++it)
                sv[it] = *reinterpret_cast<const floatx4*>(
                    &lds[U0 + (lane >> 2) * UTILE + (4 * wid + it) * USTR + (lane & 3) * 4]);

            if (k + 1 < ns) write_strip();          // strip k+1 regs -> ibuf
            if (k + 2 < ns) load_strip(s0 + k + 2); // issue loads before stores

            float* g = out + sbase(s0 + k) + (size_t)(4 * wid) * IMG_W + lane * 4;
            #pragma unroll
            for (int it = 0; it < 4; ++it)
                *reinterpret_cast<floatx4*>(g + (size_t)it * IMG_W) = sv[it];
        }
    }
}

extern "C" void kernel_launch(void* const* d_in, const int* in_sizes, int n_in,
                              void* d_out, int out_size, void* d_ws, size_t ws_size,
                              hipStream_t stream) {
    const float* x    = (const float*)d_in[0];
    const float* kern = (const float*)d_in[1];
    float* out        = (float*)d_out;

    const int n_img        = in_sizes[0] / (IMG_W * IMG_W);   // 96
    const int total_strips = n_img * 256;                     // 24576
    const int blocks       = 1024;                            // 4 per CU
    const int per_block    = (total_strips + blocks - 1) / blocks;  // 24, exact

    dct16_kernel<<<blocks, 256, 0, stream>>>(x, kern, out, per_block, total_strips);
}